// Round 4
// baseline (577.345 us; speedup 1.0000x reference)
//
#include <hip/hip_runtime.h>
#include <cmath>
#include <complex>

typedef unsigned short u16;
typedef unsigned int u32;
typedef __bf16 bf16x8 __attribute__((ext_vector_type(8)));
typedef __bf16 bf16x2 __attribute__((ext_vector_type(2)));
typedef float f32x4 __attribute__((ext_vector_type(4)));
typedef float f32x2 __attribute__((ext_vector_type(2)));

#define CD 128
#define TILE_N 8
#define XS 136   // bufX / sTP row stride (272 B, 16B-aligned)
#define LS 132   // sL / sR row stride (264 B -> 8-bank rotation per 4 rows: conflict-free)
#define GRID_BLOCKS 768  // 3 blocks/CU x 256 CUs; each block loops ~8 tiles

// region0: bufX (64 x XS) aliased with sTP (72 x XS) = 9792 elems
// sL: 64*LS = 8448 ; sR: 8448.  total 26688 u16 = 53376 B  (3 blocks/CU)
#define SMEM_TOTAL (72 * XS + 64 * LS + 64 * LS)

struct TPW { float w220[25]; float w121[45]; float w112[45]; };

// pure-C pair conversion: compiler fuses the two casts into v_cvt_pk_bf16_f32 (RNE)
__device__ __forceinline__ u32 pk2(float a, float b) {
  bf16x2 h;
  h.x = (__bf16)a;
  h.y = (__bf16)b;
  return __builtin_bit_cast(u32, h);
}
__device__ __forceinline__ f32x2 unpk(u32 v) {
  f32x2 r;
  r.x = __uint_as_float(v << 16);
  r.y = __uint_as_float(v & 0xffff0000u);
  return r;
}

// 4x uint4 burst load (64B-strided fragments); static indexing only
__device__ __forceinline__ void ldw4(uint4* dst, const u16* base) {
#pragma unroll
  for (int kk = 0; kk < 4; ++kk)
    dst[kk] = *(const uint4*)(base + kk * 32);
}

__device__ __forceinline__ f32x4 mf(const uint4& a, const uint4& b, f32x4 c) {
  return __builtin_amdgcn_mfma_f32_16x16x32_bf16(
      __builtin_bit_cast(bf16x8, a), __builtin_bit_cast(bf16x8, b), c, 0, 0, 0);
}

// stage-A epilogue: 4 consecutive rows at one column, bf16
__device__ __forceinline__ void stA(u16* d, const f32x4& a) {
  u32 p01 = pk2(a[0], a[1]);
  u32 p23 = pk2(a[2], a[3]);
  d[0]      = (u16)p01;
  d[LS]     = (u16)(p01 >> 16);
  d[2 * LS] = (u16)p23;
  d[3 * LS] = (u16)(p23 >> 16);
}

__global__ void cvt_weights_kernel(const float* __restrict__ Wl,
                                   const float* __restrict__ Wr,
                                   const float* __restrict__ Wf,
                                   u16* __restrict__ ws) {
  int idx = (blockIdx.x * 256 + threadIdx.x) * 8;   // 72 blocks -> 0..147448
  const float* src; int off;
  if (idx < 49152)      { src = Wl; off = idx; }
  else if (idx < 98304) { src = Wr; off = idx - 49152; }
  else                  { src = Wf; off = idx - 98304; }
  float4 a = *(const float4*)(src + off);
  float4 b = *(const float4*)(src + off + 4);
  uint4 v;
  v.x = pk2(a.x, a.y);
  v.y = pk2(a.z, a.w);
  v.z = pk2(b.x, b.y);
  v.w = pk2(b.z, b.w);
  *(uint4*)(ws + idx) = v;
}

__global__ __launch_bounds__(256, 3)
void fused_kernel(const float* __restrict__ x, const u16* __restrict__ ws,
                  const float* __restrict__ bfin, float* __restrict__ out,
                  int N, TPW tw) {
  __shared__ __align__(16) u16 smem[SMEM_TOTAL];
  u16* bufX = smem;                       // 64 x XS  (rows: (m-1)*8+n, m=1..8)
  u16* sTP  = smem;                       // 72 x XS  (aliases bufX; post-stage-A)
  u16* sL   = smem + 72 * XS;             // 64 x LS
  u16* sR   = smem + 72 * XS + 64 * LS;   // 64 x LS

  const int tid  = threadIdx.x;
  const int w    = tid >> 6;
  const int lane = tid & 63;
  const int q    = lane >> 4;
  const int lr   = lane & 15;

  const int mat = w >> 1;                 // 0 = left, 1 = right
  const int wl  = w & 1;
  u16* dstA = mat ? sR : sL;
  const u16* wsA = ws + mat * 3 * 16384;
  const u16* wsf = ws + 6 * 16384;

  const int dc0 = w * 16 + lr;            // stage-C cti0 col
  const int dc1 = dc0 + 64;               // stage-C cti1 col
  const float bias0 = bfin[dc0];
  const float bias1 = bfin[dc1];

  const int ntiles = (N + TILE_N - 1) / TILE_N;

  for (int tile = blockIdx.x; tile < ntiles; tile += gridDim.x) {
    const int n0 = tile * TILE_N;

    // prev tile's stage-C LDS reads must finish before bufX/sL/sR overwrite
    __syncthreads();

    // ---------- stage 0: global x (m=1..8) -> bufX (bf16) ----------
#pragma unroll
    for (int it = 0; it < 4; ++it) {
      int e = (it * 256 + tid) * 8;   // element index over [64 rows][128 c]
      int r = e >> 7;                 // 0..63 : m = 1 + r/8, n = r%8
      int c = e & 127;
      int n = n0 + (r & 7);
      if (n >= N) n = N - 1;
      int grow = (n * 9 + 1 + (r >> 3)) * CD + c;
      float4 a = *(const float4*)(x + grow);
      float4 b = *(const float4*)(x + grow + 4);
      uint4 v;
      v.x = pk2(a.x, a.y);
      v.y = pk2(a.z, a.w);
      v.z = pk2(b.x, b.y);
      v.w = pk2(b.z, b.w);
      *(uint4*)(bufX + r * XS + c) = v;
    }

    // prefetch stage-A p=0 l=1 B-frags so the L2 latency overlaps the barrier
    uint4 bfA[4], bfB[4];
    {
      const int colA0 = wl * 64 + lr;
      ldw4(bfA, wsA + 16384 + colA0 * CD + q * 8);
      ldw4(bfB, wsA + 16384 + (colA0 + 16) * CD + q * 8);
    }
    __syncthreads();

    // ---------- stage A: xl = A*W_left^T, xr = A*W_right^T (l=1,2) ----------
    // all fragment arrays statically indexed; 8 uint4 weights live at a time
#pragma unroll
    for (int p = 0; p < 2; ++p) {
      const int colA = wl * 64 + p * 32 + lr;
      const int colB = colA + 16;
      if (p == 1) {   // restore l=1 frags for p=1 columns
        ldw4(bfA, wsA + 16384 + colA * CD + q * 8);
        ldw4(bfB, wsA + 16384 + colB * CD + q * 8);
      }
      // ---- l=1 rows: block rows 0..23 ----
#pragma unroll
      for (int rt = 0; rt < 2; ++rt) {
        const int gbase = rt * 16;
        int ga = gbase + lr; if (ga > 23) ga = 23;
        uint4 av[4];
        ldw4(av, bufX + ga * XS + q * 8);
        f32x4 accA = {0.f, 0.f, 0.f, 0.f};
        f32x4 accB = {0.f, 0.f, 0.f, 0.f};
#pragma unroll
        for (int kk = 0; kk < 4; ++kk) {
          accA = mf(av[kk], bfA[kk], accA);
          accB = mf(av[kk], bfB[kk], accB);
        }
        int g0 = gbase + q * 4;       // rows multiple of 4 -> quad-uniform guard
        if (g0 < 24) {
          stA(dstA + g0 * LS + colA, accA);
          stA(dstA + g0 * LS + colB, accB);
        }
      }
      // ---- l=2 rows: block rows 24..63 ----
      ldw4(bfA, wsA + 2 * 16384 + colA * CD + q * 8);
      ldw4(bfB, wsA + 2 * 16384 + colB * CD + q * 8);
#pragma unroll
      for (int rt = 0; rt < 3; ++rt) {
        const int gbase = rt * 16;
        int ga = gbase + lr; if (ga > 39) ga = 39;
        uint4 av[4];
        ldw4(av, bufX + (24 + ga) * XS + q * 8);
        f32x4 accA = {0.f, 0.f, 0.f, 0.f};
        f32x4 accB = {0.f, 0.f, 0.f, 0.f};
#pragma unroll
        for (int kk = 0; kk < 4; ++kk) {
          accA = mf(av[kk], bfA[kk], accA);
          accB = mf(av[kk], bfB[kk], accB);
        }
        int g0 = gbase + q * 4;
        if (g0 < 40) {
          stA(dstA + (24 + g0) * LS + colA, accA);
          stA(dstA + (24 + g0) * LS + colB, accB);
        }
      }
    }
    __syncthreads();

    // ---------- stage B: channel-wise CG tensor product, packed f32x2 ----------
#pragma unroll
    for (int iter = 0; iter < 2; ++iter) {
      int id = iter * 256 + tid;          // 0..511
      int cb = (id & 63) * 2;             // even base channel
      int n  = id >> 6;                   // 0..7
      const u16* pL = sL + n * LS + cb;
      const u16* pR = sR + n * LS + cb;
      f32x2 xl1[3], xr1[3], xl2[5], xr2[5];
#pragma unroll
      for (int i = 0; i < 3; ++i) {
        xl1[i] = unpk(*(const u32*)(pL + i * 8 * LS));
        xr1[i] = unpk(*(const u32*)(pR + i * 8 * LS));
      }
#pragma unroll
      for (int j = 0; j < 5; ++j) {
        xl2[j] = unpk(*(const u32*)(pL + (24 + j * 8) * LS));
        xr2[j] = unpk(*(const u32*)(pR + (24 + j * 8) * LS));
      }
      // (2,2,0)
      f32x2 o0 = {0.f, 0.f};
#pragma unroll
      for (int i = 0; i < 5; ++i) {
        f32x2 t = {0.f, 0.f};
#pragma unroll
        for (int j = 0; j < 5; ++j) t += tw.w220[i * 5 + j] * xr2[j];
        o0 += xl2[i] * t;
      }
      // (1,2,1)
      f32x2 o1[3] = {{0.f,0.f},{0.f,0.f},{0.f,0.f}};
#pragma unroll
      for (int i = 0; i < 3; ++i)
#pragma unroll
        for (int j = 0; j < 5; ++j) {
          f32x2 pr = xl1[i] * xr2[j];
#pragma unroll
          for (int k = 0; k < 3; ++k) o1[k] += tw.w121[(i * 5 + j) * 3 + k] * pr;
        }
      // (1,1,2)
      f32x2 o2[5] = {{0.f,0.f},{0.f,0.f},{0.f,0.f},{0.f,0.f},{0.f,0.f}};
#pragma unroll
      for (int i = 0; i < 3; ++i)
#pragma unroll
        for (int j = 0; j < 3; ++j) {
          f32x2 pr = xl1[i] * xr1[j];
#pragma unroll
          for (int k = 0; k < 5; ++k) o2[k] += tw.w112[(i * 3 + j) * 5 + k] * pr;
        }
      u16* pT = sTP + n * XS + cb;
      *(u32*)(pT) = pk2(o0.x, o0.y);
#pragma unroll
      for (int k = 0; k < 3; ++k) *(u32*)(pT + (1 + k) * 8 * XS) = pk2(o1[k].x, o1[k].y);
#pragma unroll
      for (int k = 0; k < 5; ++k) *(u32*)(pT + (4 + k) * 8 * XS) = pk2(o2[k].x, o2[k].y);
    }

    // stage-C l=0 B-frags: issue before the barrier so vmcnt overlaps the sync
    uint4 bc0[4], bc1[4];
    ldw4(bc0, wsf + dc0 * CD + q * 8);
    ldw4(bc1, wsf + dc1 * CD + q * 8);
    __syncthreads();

    // ---------- stage C: out = TP * W_final^T (+ b_final on m=0), store fp32 ----------
#pragma unroll
    for (int l = 0; l < 3; ++l) {
      if (l > 0) {
        ldw4(bc0, wsf + l * 16384 + dc0 * CD + q * 8);
        ldw4(bc1, wsf + l * 16384 + dc1 * CD + q * 8);
      }
      const int rows   = (l == 0) ? 8 : (l == 1 ? 24 : 40);
      const int soff   = (l == 0) ? 0 : (l == 1 ? 8 : 32);
      const int ntl    = (l == 0) ? 1 : (l == 1 ? 2 : 3);
#pragma unroll
      for (int t = 0; t < 3; ++t) {
        if (t >= ntl) continue;
        int ga = t * 16 + lr; if (ga > rows - 1) ga = rows - 1;
        uint4 av[4];
        ldw4(av, sTP + (soff + ga) * XS + q * 8);
        f32x4 a0 = {0.f, 0.f, 0.f, 0.f};
        f32x4 a1 = {0.f, 0.f, 0.f, 0.f};
#pragma unroll
        for (int kk = 0; kk < 4; ++kk) {
          a0 = mf(av[kk], bc0[kk], a0);
          a1 = mf(av[kk], bc1[kk], a1);
        }
#pragma unroll
        for (int reg = 0; reg < 4; ++reg) {
          int gg = t * 16 + q * 4 + reg;
          if (gg < rows) {
            int m = l * l + (gg >> 3);
            int n = n0 + (gg & 7);
            if (n < N) {
              float v0 = a0[reg], v1 = a1[reg];
              if (l == 0) { v0 += bias0; v1 += bias1; }
              out[(n * 9 + m) * CD + dc0] = v0;
              out[(n * 9 + m) * CD + dc1] = v1;
            }
          }
        }
      }
    }
  }
}

// =================== host: Wigner-3j (exact port of reference) ===================
typedef std::complex<double> cd;

static double factd(int n) { double r = 1.0; for (int i = 2; i <= n; ++i) r *= i; return r; }

static double su2_cg(int j1, int m1, int j2, int m2, int j3, int m3) {
  if (m3 != m1 + m2) return 0.0;
  int vmin = -j1 + j2 + m3; if (-j1 + m1 > vmin) vmin = -j1 + m1; if (0 > vmin) vmin = 0;
  int vmax = j2 + j3 + m1; if (j3 - j1 + j2 < vmax) vmax = j3 - j1 + j2; if (j3 + m3 < vmax) vmax = j3 + m3;
  double pref = std::sqrt((2.0 * j3 + 1.0) * factd(j3 + j1 - j2) * factd(j3 - j1 + j2)
                          * factd(j1 + j2 - j3) / factd(j1 + j2 + j3 + 1)
                          * factd(j3 + m3) * factd(j3 - m3)
                          / (factd(j1 - m1) * factd(j1 + m1) * factd(j2 - m2) * factd(j2 + m2)));
  double s = 0.0;
  for (int v = vmin; v <= vmax; ++v) {
    double sgn = ((v + j2 + m2) & 1) ? -1.0 : 1.0;
    s += sgn / factd(v) * factd(j2 + j3 + m1 - v) * factd(j1 - m1 + v)
         / (factd(j3 - j1 + j2 - v) * factd(j3 + m3 - v) * factd(v + j1 - j2 - m3));
  }
  return pref * s;
}

static void qmat(int l, cd q[5][5]) {
  for (int a = 0; a < 5; ++a) for (int b = 0; b < 5; ++b) q[a][b] = 0.0;
  const double is2 = 1.0 / std::sqrt(2.0);
  for (int m = -l; m < 0; ++m) {
    q[l + m][l - m] = is2;            // q[l+m, l+|m|]
    q[l + m][l + m] = cd(0.0, -is2);  // q[l+m, l-|m|]
  }
  q[l][l] = 1.0;
  for (int m = 1; m <= l; ++m) {
    double s = (m & 1) ? -1.0 : 1.0;
    q[l + m][l + m] = s * is2;
    q[l + m][l - m] = cd(0.0, s * is2);
  }
  cd f(1.0, 0.0);
  for (int i = 0; i < l; ++i) f *= cd(0.0, -1.0);  // (-1j)^l
  for (int a = 0; a < 5; ++a) for (int b = 0; b < 5; ++b) q[a][b] *= f;
}

static void wigner3j(int l1, int l2, int l3, double* C) {  // flat [d1][d2][d3]
  int d1 = 2 * l1 + 1, d2 = 2 * l2 + 1, d3 = 2 * l3 + 1;
  cd Q1[5][5], Q2[5][5], Q3[5][5];
  qmat(l1, Q1); qmat(l2, Q2); qmat(l3, Q3);
  cd Csu2[5][5][5];
  for (int i = 0; i < d1; ++i)
    for (int k = 0; k < d2; ++k)
      for (int n = 0; n < d3; ++n)
        Csu2[i][k][n] = su2_cg(l1, i - l1, l2, k - l2, l3, n - l3);
  double norm = 0.0;
  for (int j = 0; j < d1; ++j)
    for (int lx = 0; lx < d2; ++lx)
      for (int m = 0; m < d3; ++m) {
        cd acc(0.0, 0.0);
        for (int i = 0; i < d1; ++i)
          for (int k = 0; k < d2; ++k)
            for (int n = 0; n < d3; ++n)
              acc += Q1[i][j] * Q2[k][lx] * std::conj(Q3[n][m]) * Csu2[i][k][n];
        C[(j * d2 + lx) * d3 + m] = acc.real();
        norm += acc.real() * acc.real();
      }
  norm = std::sqrt(norm);
  for (int t = 0; t < d1 * d2 * d3; ++t) C[t] /= norm;
}

extern "C" void kernel_launch(void* const* d_in, const int* in_sizes, int n_in,
                              void* d_out, int out_size, void* d_ws, size_t ws_size,
                              hipStream_t stream) {
  const float* x    = (const float*)d_in[0];
  const float* Wl   = (const float*)d_in[1];
  const float* Wr   = (const float*)d_in[3];
  const float* Wf   = (const float*)d_in[5];
  const float* bfin = (const float*)d_in[6];
  float* out = (float*)d_out;
  const int N = in_sizes[0] / (9 * CD);

  TPW tw;
  double c220[25], c121[45], c112[45];
  wigner3j(2, 2, 0, c220);
  wigner3j(1, 2, 1, c121);
  wigner3j(1, 1, 2, c112);
  const double a1 = std::sqrt(3.0), a2 = std::sqrt(5.0);
  for (int i = 0; i < 25; ++i) tw.w220[i] = (float)c220[i];          // alpha = 1
  for (int i = 0; i < 45; ++i) tw.w121[i] = (float)(a1 * c121[i]);
  for (int i = 0; i < 45; ++i) tw.w112[i] = (float)(a2 * c112[i]);

  u16* ws = (u16*)d_ws;  // 147456 bf16 = 294912 B
  cvt_weights_kernel<<<72, 256, 0, stream>>>(Wl, Wr, Wf, ws);
  int ntiles = (N + TILE_N - 1) / TILE_N;
  int grid = ntiles < GRID_BLOCKS ? ntiles : GRID_BLOCKS;
  fused_kernel<<<grid, 256, 0, stream>>>(x, ws, bfin, out, N, tw);
}

// Round 5
// 495.739 us; speedup vs baseline: 1.1646x; 1.1646x over previous
//
#include <hip/hip_runtime.h>
#include <cmath>
#include <complex>

typedef unsigned short u16;
typedef unsigned int u32;
typedef __bf16 bf16x8 __attribute__((ext_vector_type(8)));
typedef __bf16 bf16x2 __attribute__((ext_vector_type(2)));
typedef float f32x4 __attribute__((ext_vector_type(4)));
typedef float f32x2 __attribute__((ext_vector_type(2)));

#define CD 128
#define TILE_N 8
#define XS 136   // bufX / sTP row stride (272 B, 16B-aligned)
#define LS 132   // sL / sR row stride (264 B -> 8-bank rotation per 4 rows: conflict-free)

// region0: bufX (64 x XS) aliased with sTP (72 x XS) = 9792 elems
// sL: 64*LS = 8448 ; sR: 8448.  total 26688 u16 = 53376 B  (3 blocks/CU)
#define SMEM_TOTAL (72 * XS + 64 * LS + 64 * LS)

struct TPW { float w220[25]; float w121[45]; float w112[45]; };

// pure-C pair conversion: compiler fuses the two casts into v_cvt_pk_bf16_f32 (RNE)
__device__ __forceinline__ u32 pk2(float a, float b) {
  bf16x2 h;
  h.x = (__bf16)a;
  h.y = (__bf16)b;
  return __builtin_bit_cast(u32, h);
}
__device__ __forceinline__ f32x2 unpk(u32 v) {
  f32x2 r;
  r.x = __uint_as_float(v << 16);
  r.y = __uint_as_float(v & 0xffff0000u);
  return r;
}

// 4x uint4 burst load (64B-strided fragments); static indexing only
__device__ __forceinline__ void ldw4(uint4* dst, const u16* base) {
#pragma unroll
  for (int kk = 0; kk < 4; ++kk)
    dst[kk] = *(const uint4*)(base + kk * 32);
}

__device__ __forceinline__ f32x4 mf(const uint4& a, const uint4& b, f32x4 c) {
  return __builtin_amdgcn_mfma_f32_16x16x32_bf16(
      __builtin_bit_cast(bf16x8, a), __builtin_bit_cast(bf16x8, b), c, 0, 0, 0);
}

// stage-A epilogue: 4 consecutive rows at one column, bf16
__device__ __forceinline__ void stA(u16* d, const f32x4& a) {
  u32 p01 = pk2(a[0], a[1]);
  u32 p23 = pk2(a[2], a[3]);
  d[0]      = (u16)p01;
  d[LS]     = (u16)(p01 >> 16);
  d[2 * LS] = (u16)p23;
  d[3 * LS] = (u16)(p23 >> 16);
}

__global__ void cvt_weights_kernel(const float* __restrict__ Wl,
                                   const float* __restrict__ Wr,
                                   const float* __restrict__ Wf,
                                   u16* __restrict__ ws) {
  int idx = (blockIdx.x * 256 + threadIdx.x) * 8;   // 72 blocks -> 0..147448
  const float* src; int off;
  if (idx < 49152)      { src = Wl; off = idx; }
  else if (idx < 98304) { src = Wr; off = idx - 49152; }
  else                  { src = Wf; off = idx - 98304; }
  float4 a = *(const float4*)(src + off);
  float4 b = *(const float4*)(src + off + 4);
  uint4 v;
  v.x = pk2(a.x, a.y);
  v.y = pk2(a.z, a.w);
  v.z = pk2(b.x, b.y);
  v.w = pk2(b.z, b.w);
  *(uint4*)(ws + idx) = v;
}

__global__ __launch_bounds__(256, 3)
void fused_kernel(const float* __restrict__ x, const u16* __restrict__ ws,
                  const float* __restrict__ bfin, float* __restrict__ out,
                  int N, TPW tw) {
  __shared__ __align__(16) u16 smem[SMEM_TOTAL];
  u16* bufX = smem;                       // 64 x XS  (rows: (m-1)*8+n, m=1..8)
  u16* sTP  = smem;                       // 72 x XS  (aliases bufX; post-stage-A)
  u16* sL   = smem + 72 * XS;             // 64 x LS
  u16* sR   = smem + 72 * XS + 64 * LS;   // 64 x LS

  const int tid  = threadIdx.x;
  const int n0   = blockIdx.x * TILE_N;
  const int w    = tid >> 6;
  const int lane = tid & 63;
  const int q    = lane >> 4;
  const int lr   = lane & 15;

  const int mat = w >> 1;                 // 0 = left, 1 = right
  const int wl  = w & 1;
  u16* dstA = mat ? sR : sL;
  const u16* wsA = ws + mat * 3 * 16384;
  const u16* wsf = ws + 6 * 16384;

  const int dc0 = w * 16 + lr;            // stage-C cti0 col
  const int dc1 = dc0 + 64;               // stage-C cti1 col
  const float bias0 = bfin[dc0];
  const float bias1 = bfin[dc1];

  // ---------- stage 0: global x (m=1..8) -> bufX (bf16) ----------
#pragma unroll
  for (int it = 0; it < 4; ++it) {
    int e = (it * 256 + tid) * 8;   // element index over [64 rows][128 c]
    int r = e >> 7;                 // 0..63 : m = 1 + r/8, n = r%8
    int c = e & 127;
    int n = n0 + (r & 7);
    if (n >= N) n = N - 1;
    int grow = (n * 9 + 1 + (r >> 3)) * CD + c;
    float4 a = *(const float4*)(x + grow);
    float4 b = *(const float4*)(x + grow + 4);
    uint4 v;
    v.x = pk2(a.x, a.y);
    v.y = pk2(a.z, a.w);
    v.z = pk2(b.x, b.y);
    v.w = pk2(b.z, b.w);
    *(uint4*)(bufX + r * XS + c) = v;
  }

  // prefetch stage-A p=0 l=1 B-frags so the L2 latency overlaps the barrier
  uint4 bfA[4], bfB[4];
  {
    const int colA0 = wl * 64 + lr;
    ldw4(bfA, wsA + 16384 + colA0 * CD + q * 8);
    ldw4(bfB, wsA + 16384 + (colA0 + 16) * CD + q * 8);
  }
  __syncthreads();

  // ---------- stage A: xl = A*W_left^T, xr = A*W_right^T (l=1,2) ----------
  // all fragment arrays statically indexed; 8 uint4 weights live at a time
#pragma unroll
  for (int p = 0; p < 2; ++p) {
    const int colA = wl * 64 + p * 32 + lr;
    const int colB = colA + 16;
    if (p == 1) {   // restore l=1 frags for p=1 columns
      ldw4(bfA, wsA + 16384 + colA * CD + q * 8);
      ldw4(bfB, wsA + 16384 + colB * CD + q * 8);
    }
    // ---- l=1 rows: block rows 0..23 ----
#pragma unroll
    for (int rt = 0; rt < 2; ++rt) {
      const int gbase = rt * 16;
      int ga = gbase + lr; if (ga > 23) ga = 23;
      uint4 av[4];
      ldw4(av, bufX + ga * XS + q * 8);
      f32x4 accA = {0.f, 0.f, 0.f, 0.f};
      f32x4 accB = {0.f, 0.f, 0.f, 0.f};
#pragma unroll
      for (int kk = 0; kk < 4; ++kk) {
        accA = mf(av[kk], bfA[kk], accA);
        accB = mf(av[kk], bfB[kk], accB);
      }
      int g0 = gbase + q * 4;       // rows multiple of 4 -> quad-uniform guard
      if (g0 < 24) {
        stA(dstA + g0 * LS + colA, accA);
        stA(dstA + g0 * LS + colB, accB);
      }
    }
    // ---- l=2 rows: block rows 24..63 ----
    ldw4(bfA, wsA + 2 * 16384 + colA * CD + q * 8);
    ldw4(bfB, wsA + 2 * 16384 + colB * CD + q * 8);
#pragma unroll
    for (int rt = 0; rt < 3; ++rt) {
      const int gbase = rt * 16;
      int ga = gbase + lr; if (ga > 39) ga = 39;
      uint4 av[4];
      ldw4(av, bufX + (24 + ga) * XS + q * 8);
      f32x4 accA = {0.f, 0.f, 0.f, 0.f};
      f32x4 accB = {0.f, 0.f, 0.f, 0.f};
#pragma unroll
      for (int kk = 0; kk < 4; ++kk) {
        accA = mf(av[kk], bfA[kk], accA);
        accB = mf(av[kk], bfB[kk], accB);
      }
      int g0 = gbase + q * 4;
      if (g0 < 40) {
        stA(dstA + (24 + g0) * LS + colA, accA);
        stA(dstA + (24 + g0) * LS + colB, accB);
      }
    }
  }
  __syncthreads();

  // ---------- stage B: channel-wise CG tensor product, packed f32x2 ----------
#pragma unroll
  for (int iter = 0; iter < 2; ++iter) {
    int id = iter * 256 + tid;          // 0..511
    int cb = (id & 63) * 2;             // even base channel
    int n  = id >> 6;                   // 0..7
    const u16* pL = sL + n * LS + cb;
    const u16* pR = sR + n * LS + cb;
    f32x2 xl1[3], xr1[3], xl2[5], xr2[5];
#pragma unroll
    for (int i = 0; i < 3; ++i) {
      xl1[i] = unpk(*(const u32*)(pL + i * 8 * LS));
      xr1[i] = unpk(*(const u32*)(pR + i * 8 * LS));
    }
#pragma unroll
    for (int j = 0; j < 5; ++j) {
      xl2[j] = unpk(*(const u32*)(pL + (24 + j * 8) * LS));
      xr2[j] = unpk(*(const u32*)(pR + (24 + j * 8) * LS));
    }
    // (2,2,0)
    f32x2 o0 = {0.f, 0.f};
#pragma unroll
    for (int i = 0; i < 5; ++i) {
      f32x2 t = {0.f, 0.f};
#pragma unroll
      for (int j = 0; j < 5; ++j) t += tw.w220[i * 5 + j] * xr2[j];
      o0 += xl2[i] * t;
    }
    // (1,2,1)
    f32x2 o1[3] = {{0.f,0.f},{0.f,0.f},{0.f,0.f}};
#pragma unroll
    for (int i = 0; i < 3; ++i)
#pragma unroll
      for (int j = 0; j < 5; ++j) {
        f32x2 pr = xl1[i] * xr2[j];
#pragma unroll
        for (int k = 0; k < 3; ++k) o1[k] += tw.w121[(i * 5 + j) * 3 + k] * pr;
      }
    // (1,1,2)
    f32x2 o2[5] = {{0.f,0.f},{0.f,0.f},{0.f,0.f},{0.f,0.f},{0.f,0.f}};
#pragma unroll
    for (int i = 0; i < 3; ++i)
#pragma unroll
      for (int j = 0; j < 3; ++j) {
        f32x2 pr = xl1[i] * xr1[j];
#pragma unroll
        for (int k = 0; k < 5; ++k) o2[k] += tw.w112[(i * 3 + j) * 5 + k] * pr;
      }
    u16* pT = sTP + n * XS + cb;
    *(u32*)(pT) = pk2(o0.x, o0.y);
#pragma unroll
    for (int k = 0; k < 3; ++k) *(u32*)(pT + (1 + k) * 8 * XS) = pk2(o1[k].x, o1[k].y);
#pragma unroll
    for (int k = 0; k < 5; ++k) *(u32*)(pT + (4 + k) * 8 * XS) = pk2(o2[k].x, o2[k].y);
  }

  // stage-C l=0 B-frags: issue before the barrier so vmcnt overlaps the sync
  uint4 bc0[4], bc1[4];
  ldw4(bc0, wsf + dc0 * CD + q * 8);
  ldw4(bc1, wsf + dc1 * CD + q * 8);
  __syncthreads();

  // ---------- stage C: out = TP * W_final^T (+ b_final on m=0), store fp32 ----------
#pragma unroll
  for (int l = 0; l < 3; ++l) {
    if (l > 0) {
      ldw4(bc0, wsf + l * 16384 + dc0 * CD + q * 8);
      ldw4(bc1, wsf + l * 16384 + dc1 * CD + q * 8);
    }
    const int rows   = (l == 0) ? 8 : (l == 1 ? 24 : 40);
    const int soff   = (l == 0) ? 0 : (l == 1 ? 8 : 32);
    const int ntl    = (l == 0) ? 1 : (l == 1 ? 2 : 3);
#pragma unroll
    for (int t = 0; t < 3; ++t) {
      if (t >= ntl) continue;
      int ga = t * 16 + lr; if (ga > rows - 1) ga = rows - 1;
      uint4 av[4];
      ldw4(av, sTP + (soff + ga) * XS + q * 8);
      f32x4 a0 = {0.f, 0.f, 0.f, 0.f};
      f32x4 a1 = {0.f, 0.f, 0.f, 0.f};
#pragma unroll
      for (int kk = 0; kk < 4; ++kk) {
        a0 = mf(av[kk], bc0[kk], a0);
        a1 = mf(av[kk], bc1[kk], a1);
      }
#pragma unroll
      for (int reg = 0; reg < 4; ++reg) {
        int gg = t * 16 + q * 4 + reg;
        if (gg < rows) {
          int m = l * l + (gg >> 3);
          int n = n0 + (gg & 7);
          if (n < N) {
            float v0 = a0[reg], v1 = a1[reg];
            if (l == 0) { v0 += bias0; v1 += bias1; }
            out[(n * 9 + m) * CD + dc0] = v0;
            out[(n * 9 + m) * CD + dc1] = v1;
          }
        }
      }
    }
  }
}

// =================== host: Wigner-3j (exact port of reference) ===================
typedef std::complex<double> cd;

static double factd(int n) { double r = 1.0; for (int i = 2; i <= n; ++i) r *= i; return r; }

static double su2_cg(int j1, int m1, int j2, int m2, int j3, int m3) {
  if (m3 != m1 + m2) return 0.0;
  int vmin = -j1 + j2 + m3; if (-j1 + m1 > vmin) vmin = -j1 + m1; if (0 > vmin) vmin = 0;
  int vmax = j2 + j3 + m1; if (j3 - j1 + j2 < vmax) vmax = j3 - j1 + j2; if (j3 + m3 < vmax) vmax = j3 + m3;
  double pref = std::sqrt((2.0 * j3 + 1.0) * factd(j3 + j1 - j2) * factd(j3 - j1 + j2)
                          * factd(j1 + j2 - j3) / factd(j1 + j2 + j3 + 1)
                          * factd(j3 + m3) * factd(j3 - m3)
                          / (factd(j1 - m1) * factd(j1 + m1) * factd(j2 - m2) * factd(j2 + m2)));
  double s = 0.0;
  for (int v = vmin; v <= vmax; ++v) {
    double sgn = ((v + j2 + m2) & 1) ? -1.0 : 1.0;
    s += sgn / factd(v) * factd(j2 + j3 + m1 - v) * factd(j1 - m1 + v)
         / (factd(j3 - j1 + j2 - v) * factd(j3 + m3 - v) * factd(v + j1 - j2 - m3));
  }
  return pref * s;
}

static void qmat(int l, cd q[5][5]) {
  for (int a = 0; a < 5; ++a) for (int b = 0; b < 5; ++b) q[a][b] = 0.0;
  const double is2 = 1.0 / std::sqrt(2.0);
  for (int m = -l; m < 0; ++m) {
    q[l + m][l - m] = is2;            // q[l+m, l+|m|]
    q[l + m][l + m] = cd(0.0, -is2);  // q[l+m, l-|m|]
  }
  q[l][l] = 1.0;
  for (int m = 1; m <= l; ++m) {
    double s = (m & 1) ? -1.0 : 1.0;
    q[l + m][l + m] = s * is2;
    q[l + m][l - m] = cd(0.0, s * is2);
  }
  cd f(1.0, 0.0);
  for (int i = 0; i < l; ++i) f *= cd(0.0, -1.0);  // (-1j)^l
  for (int a = 0; a < 5; ++a) for (int b = 0; b < 5; ++b) q[a][b] *= f;
}

static void wigner3j(int l1, int l2, int l3, double* C) {  // flat [d1][d2][d3]
  int d1 = 2 * l1 + 1, d2 = 2 * l2 + 1, d3 = 2 * l3 + 1;
  cd Q1[5][5], Q2[5][5], Q3[5][5];
  qmat(l1, Q1); qmat(l2, Q2); qmat(l3, Q3);
  cd Csu2[5][5][5];
  for (int i = 0; i < d1; ++i)
    for (int k = 0; k < d2; ++k)
      for (int n = 0; n < d3; ++n)
        Csu2[i][k][n] = su2_cg(l1, i - l1, l2, k - l2, l3, n - l3);
  double norm = 0.0;
  for (int j = 0; j < d1; ++j)
    for (int lx = 0; lx < d2; ++lx)
      for (int m = 0; m < d3; ++m) {
        cd acc(0.0, 0.0);
        for (int i = 0; i < d1; ++i)
          for (int k = 0; k < d2; ++k)
            for (int n = 0; n < d3; ++n)
              acc += Q1[i][j] * Q2[k][lx] * std::conj(Q3[n][m]) * Csu2[i][k][n];
        C[(j * d2 + lx) * d3 + m] = acc.real();
        norm += acc.real() * acc.real();
      }
  norm = std::sqrt(norm);
  for (int t = 0; t < d1 * d2 * d3; ++t) C[t] /= norm;
}

extern "C" void kernel_launch(void* const* d_in, const int* in_sizes, int n_in,
                              void* d_out, int out_size, void* d_ws, size_t ws_size,
                              hipStream_t stream) {
  const float* x    = (const float*)d_in[0];
  const float* Wl   = (const float*)d_in[1];
  const float* Wr   = (const float*)d_in[3];
  const float* Wf   = (const float*)d_in[5];
  const float* bfin = (const float*)d_in[6];
  float* out = (float*)d_out;
  const int N = in_sizes[0] / (9 * CD);

  TPW tw;
  double c220[25], c121[45], c112[45];
  wigner3j(2, 2, 0, c220);
  wigner3j(1, 2, 1, c121);
  wigner3j(1, 1, 2, c112);
  const double a1 = std::sqrt(3.0), a2 = std::sqrt(5.0);
  for (int i = 0; i < 25; ++i) tw.w220[i] = (float)c220[i];          // alpha = 1
  for (int i = 0; i < 45; ++i) tw.w121[i] = (float)(a1 * c121[i]);
  for (int i = 0; i < 45; ++i) tw.w112[i] = (float)(a2 * c112[i]);

  u16* ws = (u16*)d_ws;  // 147456 bf16 = 294912 B
  cvt_weights_kernel<<<72, 256, 0, stream>>>(Wl, Wr, Wf, ws);
  int grid = (N + TILE_N - 1) / TILE_N;
  fused_kernel<<<grid, 256, 0, stream>>>(x, ws, bfin, out, N, tw);
}

// Round 6
// 493.920 us; speedup vs baseline: 1.1689x; 1.0037x over previous
//
#include <hip/hip_runtime.h>
#include <cmath>
#include <complex>

typedef unsigned short u16;
typedef unsigned int u32;
typedef __bf16 bf16x8 __attribute__((ext_vector_type(8)));
typedef __bf16 bf16x2 __attribute__((ext_vector_type(2)));
typedef float f32x4 __attribute__((ext_vector_type(4)));
typedef float f32x2 __attribute__((ext_vector_type(2)));

#define CD 128
#define TILE_N 8
#define XS 136   // bufX / sTP row stride (272 B, 16B-aligned for b128)
#define CS 66    // sL / sR per-CHANNEL stride in u16 (132 B -> +1 bank/ch: conflict-free)

// region0: bufX (64 x XS) aliased with sTP (72 x XS) = 9792 elems
// sL: 128*CS = 8448 ; sR: 8448.  total 26688 u16 = 53376 B  (3 blocks/CU)
#define SMEM_TOTAL (72 * XS + 2 * 128 * CS)

struct TPW { float w220[25]; float w121[45]; float w112[45]; };

// pure-C pair conversion: compiler fuses the two casts into v_cvt_pk_bf16_f32 (RNE)
__device__ __forceinline__ u32 pk2(float a, float b) {
  bf16x2 h;
  h.x = (__bf16)a;
  h.y = (__bf16)b;
  return __builtin_bit_cast(u32, h);
}
__device__ __forceinline__ f32x2 unpk(u32 v) {
  f32x2 r;
  r.x = __uint_as_float(v << 16);
  r.y = __uint_as_float(v & 0xffff0000u);
  return r;
}

// 4x uint4 burst load (64B-strided fragments); static indexing only
__device__ __forceinline__ void ldw4(uint4* dst, const u16* base) {
#pragma unroll
  for (int kk = 0; kk < 4; ++kk)
    dst[kk] = *(const uint4*)(base + kk * 32);
}

__device__ __forceinline__ f32x4 mf(const uint4& a, const uint4& b, f32x4 c) {
  return __builtin_amdgcn_mfma_f32_16x16x32_bf16(
      __builtin_bit_cast(bf16x8, a), __builtin_bit_cast(bf16x8, b), c, 0, 0, 0);
}

// stage-A epilogue: 4 consecutive ROWS of one channel-column -> contiguous 8 B
// in channel-major sL/sR (two adjacent u32 stores -> single ds_write2_b32)
__device__ __forceinline__ void stA(u16* d, const f32x4& a) {
  u32* p = (u32*)d;            // byte addr = ch*132 + g0*2, always 4-aligned
  p[0] = pk2(a[0], a[1]);
  p[1] = pk2(a[2], a[3]);
}

__global__ void cvt_weights_kernel(const float* __restrict__ Wl,
                                   const float* __restrict__ Wr,
                                   const float* __restrict__ Wf,
                                   u16* __restrict__ ws) {
  int idx = (blockIdx.x * 256 + threadIdx.x) * 8;   // 72 blocks -> 0..147448
  const float* src; int off;
  if (idx < 49152)      { src = Wl; off = idx; }
  else if (idx < 98304) { src = Wr; off = idx - 49152; }
  else                  { src = Wf; off = idx - 98304; }
  float4 a = *(const float4*)(src + off);
  float4 b = *(const float4*)(src + off + 4);
  uint4 v;
  v.x = pk2(a.x, a.y);
  v.y = pk2(a.z, a.w);
  v.z = pk2(b.x, b.y);
  v.w = pk2(b.z, b.w);
  *(uint4*)(ws + idx) = v;
}

__global__ __launch_bounds__(256, 3)
void fused_kernel(const float* __restrict__ x, const u16* __restrict__ ws,
                  const float* __restrict__ bfin, float* __restrict__ out,
                  int N, TPW tw) {
  __shared__ __align__(16) u16 smem[SMEM_TOTAL];
  u16* bufX = smem;                       // 64 x XS  (rows: (m-1)*8+n, m=1..8)
  u16* sTP  = smem;                       // 72 x XS  (aliases bufX; post-stage-A)
  u16* sL   = smem + 72 * XS;             // 128 ch x CS  (channel-major!)
  u16* sR   = sL + 128 * CS;              // 128 ch x CS

  const int tid  = threadIdx.x;
  const int n0   = blockIdx.x * TILE_N;
  const int w    = tid >> 6;
  const int lane = tid & 63;
  const int q    = lane >> 4;
  const int lr   = lane & 15;

  const int mat = w >> 1;                 // 0 = left, 1 = right
  const int wl  = w & 1;
  u16* dstA = mat ? sR : sL;
  const u16* wsA = ws + mat * 3 * 16384;
  const u16* wsf = ws + 6 * 16384;

  const int dc0 = w * 16 + lr;            // stage-C cti0 col
  const int dc1 = dc0 + 64;               // stage-C cti1 col
  const float bias0 = bfin[dc0];
  const float bias1 = bfin[dc1];

  // ---------- stage 0: global x (m=1..8) -> bufX (bf16) ----------
#pragma unroll
  for (int it = 0; it < 4; ++it) {
    int e = (it * 256 + tid) * 8;   // element index over [64 rows][128 c]
    int r = e >> 7;                 // 0..63 : m = 1 + r/8, n = r%8
    int c = e & 127;
    int n = n0 + (r & 7);
    if (n >= N) n = N - 1;
    int grow = (n * 9 + 1 + (r >> 3)) * CD + c;
    float4 a = *(const float4*)(x + grow);
    float4 b = *(const float4*)(x + grow + 4);
    uint4 v;
    v.x = pk2(a.x, a.y);
    v.y = pk2(a.z, a.w);
    v.z = pk2(b.x, b.y);
    v.w = pk2(b.z, b.w);
    *(uint4*)(bufX + r * XS + c) = v;
  }

  // prefetch ALL l=1 B-frags (4 col-tiles) so L2 latency overlaps the barrier
  const int colb = wl * 64 + lr;          // + ct*16 per col-tile
  uint4 wf0[4], wf1[4], wf2[4], wf3[4];
  ldw4(wf0, wsA + 16384 + (colb     ) * CD + q * 8);
  ldw4(wf1, wsA + 16384 + (colb + 16) * CD + q * 8);
  ldw4(wf2, wsA + 16384 + (colb + 32) * CD + q * 8);
  ldw4(wf3, wsA + 16384 + (colb + 48) * CD + q * 8);
  __syncthreads();

  // ---------- stage A: xl = A*W_left^T, xr = A*W_right^T (l=1,2) ----------
  // p-merged: each bufX row-tile read ONCE, 4 col-tiles of MFMA per read.
  // ---- l=1 rows: block rows 0..23 ----
#pragma unroll
  for (int rt = 0; rt < 2; ++rt) {
    const int gbase = rt * 16;
    int ga = gbase + lr; if (ga > 23) ga = 23;
    uint4 av[4];
    ldw4(av, bufX + ga * XS + q * 8);
    f32x4 a0 = {0.f,0.f,0.f,0.f}, a1 = {0.f,0.f,0.f,0.f};
    f32x4 a2 = {0.f,0.f,0.f,0.f}, a3 = {0.f,0.f,0.f,0.f};
#pragma unroll
    for (int kk = 0; kk < 4; ++kk) {
      a0 = mf(av[kk], wf0[kk], a0);
      a1 = mf(av[kk], wf1[kk], a1);
      a2 = mf(av[kk], wf2[kk], a2);
      a3 = mf(av[kk], wf3[kk], a3);
    }
    int g0 = gbase + q * 4;       // rows multiple of 4 -> quad-uniform guard
    if (g0 < 24) {
      stA(dstA + (colb     ) * CS + g0, a0);
      stA(dstA + (colb + 16) * CS + g0, a1);
      stA(dstA + (colb + 32) * CS + g0, a2);
      stA(dstA + (colb + 48) * CS + g0, a3);
    }
  }
  // ---- l=2 rows: block rows 24..63 ----
  ldw4(wf0, wsA + 2 * 16384 + (colb     ) * CD + q * 8);
  ldw4(wf1, wsA + 2 * 16384 + (colb + 16) * CD + q * 8);
  ldw4(wf2, wsA + 2 * 16384 + (colb + 32) * CD + q * 8);
  ldw4(wf3, wsA + 2 * 16384 + (colb + 48) * CD + q * 8);
#pragma unroll
  for (int rt = 0; rt < 3; ++rt) {
    const int gbase = rt * 16;
    int ga = gbase + lr; if (ga > 39) ga = 39;
    uint4 av[4];
    ldw4(av, bufX + (24 + ga) * XS + q * 8);
    f32x4 a0 = {0.f,0.f,0.f,0.f}, a1 = {0.f,0.f,0.f,0.f};
    f32x4 a2 = {0.f,0.f,0.f,0.f}, a3 = {0.f,0.f,0.f,0.f};
#pragma unroll
    for (int kk = 0; kk < 4; ++kk) {
      a0 = mf(av[kk], wf0[kk], a0);
      a1 = mf(av[kk], wf1[kk], a1);
      a2 = mf(av[kk], wf2[kk], a2);
      a3 = mf(av[kk], wf3[kk], a3);
    }
    int g0 = gbase + q * 4;
    if (g0 < 40) {
      stA(dstA + (colb     ) * CS + 24 + g0, a0);
      stA(dstA + (colb + 16) * CS + 24 + g0, a1);
      stA(dstA + (colb + 32) * CS + 24 + g0, a2);
      stA(dstA + (colb + 48) * CS + 24 + g0, a3);
    }
  }
  __syncthreads();

  // ---------- stage B: channel-wise CG tensor product, packed f32x2 (1 ch x 2 n) ----------
#pragma unroll
  for (int iter = 0; iter < 2; ++iter) {
    int id = iter * 256 + tid;          // 0..511
    int ch = id & 127;                  // channel (wave = 64 consecutive ch)
    int n  = (id >> 7) * 2;             // even n; pair (n, n+1)
    const u16* pL = sL + ch * CS + n;
    const u16* pR = sR + ch * CS + n;
    f32x2 xl1[3], xr1[3], xl2[5], xr2[5];
#pragma unroll
    for (int i = 0; i < 3; ++i) {
      xl1[i] = unpk(*(const u32*)(pL + i * 8));        // rows i*8+n, +n+1
      xr1[i] = unpk(*(const u32*)(pR + i * 8));
    }
#pragma unroll
    for (int j = 0; j < 5; ++j) {
      xl2[j] = unpk(*(const u32*)(pL + 24 + j * 8));
      xr2[j] = unpk(*(const u32*)(pR + 24 + j * 8));
    }
    // (2,2,0)
    f32x2 o0 = {0.f, 0.f};
#pragma unroll
    for (int i = 0; i < 5; ++i) {
      f32x2 t = {0.f, 0.f};
#pragma unroll
      for (int j = 0; j < 5; ++j) t += tw.w220[i * 5 + j] * xr2[j];
      o0 += xl2[i] * t;
    }
    // (1,2,1)
    f32x2 o1[3] = {{0.f,0.f},{0.f,0.f},{0.f,0.f}};
#pragma unroll
    for (int i = 0; i < 3; ++i)
#pragma unroll
      for (int j = 0; j < 5; ++j) {
        f32x2 pr = xl1[i] * xr2[j];
#pragma unroll
        for (int k = 0; k < 3; ++k) o1[k] += tw.w121[(i * 5 + j) * 3 + k] * pr;
      }
    // (1,1,2)
    f32x2 o2[5] = {{0.f,0.f},{0.f,0.f},{0.f,0.f},{0.f,0.f},{0.f,0.f}};
#pragma unroll
    for (int i = 0; i < 3; ++i)
#pragma unroll
      for (int j = 0; j < 3; ++j) {
        f32x2 pr = xl1[i] * xr1[j];
#pragma unroll
        for (int k = 0; k < 5; ++k) o2[k] += tw.w112[(i * 3 + j) * 5 + k] * pr;
      }
    // sTP stays row-major [m_out*8+n][ch]; .x -> row n, .y -> row n+1
    u16* pT = sTP + n * XS + ch;
    u32 v0 = pk2(o0.x, o0.y);
    pT[0]  = (u16)v0;
    pT[XS] = (u16)(v0 >> 16);
#pragma unroll
    for (int k = 0; k < 3; ++k) {
      u32 v = pk2(o1[k].x, o1[k].y);
      u16* b = pT + (1 + k) * 8 * XS;
      b[0]  = (u16)v;
      b[XS] = (u16)(v >> 16);
    }
#pragma unroll
    for (int k = 0; k < 5; ++k) {
      u32 v = pk2(o2[k].x, o2[k].y);
      u16* b = pT + (4 + k) * 8 * XS;
      b[0]  = (u16)v;
      b[XS] = (u16)(v >> 16);
    }
  }

  // stage-C l=0 B-frags: issue before the barrier so vmcnt overlaps the sync
  uint4 bc0[4], bc1[4];
  ldw4(bc0, wsf + dc0 * CD + q * 8);
  ldw4(bc1, wsf + dc1 * CD + q * 8);
  __syncthreads();

  // ---------- stage C: out = TP * W_final^T (+ b_final on m=0), store fp32 ----------
#pragma unroll
  for (int l = 0; l < 3; ++l) {
    if (l > 0) {
      ldw4(bc0, wsf + l * 16384 + dc0 * CD + q * 8);
      ldw4(bc1, wsf + l * 16384 + dc1 * CD + q * 8);
    }
    const int rows   = (l == 0) ? 8 : (l == 1 ? 24 : 40);
    const int soff   = (l == 0) ? 0 : (l == 1 ? 8 : 32);
    const int ntl    = (l == 0) ? 1 : (l == 1 ? 2 : 3);
#pragma unroll
    for (int t = 0; t < 3; ++t) {
      if (t >= ntl) continue;
      int ga = t * 16 + lr; if (ga > rows - 1) ga = rows - 1;
      uint4 av[4];
      ldw4(av, sTP + (soff + ga) * XS + q * 8);
      f32x4 a0 = {0.f, 0.f, 0.f, 0.f};
      f32x4 a1 = {0.f, 0.f, 0.f, 0.f};
#pragma unroll
      for (int kk = 0; kk < 4; ++kk) {
        a0 = mf(av[kk], bc0[kk], a0);
        a1 = mf(av[kk], bc1[kk], a1);
      }
#pragma unroll
      for (int reg = 0; reg < 4; ++reg) {
        int gg = t * 16 + q * 4 + reg;
        if (gg < rows) {
          int m = l * l + (gg >> 3);
          int n = n0 + (gg & 7);
          if (n < N) {
            float v0 = a0[reg], v1 = a1[reg];
            if (l == 0) { v0 += bias0; v1 += bias1; }
            out[(n * 9 + m) * CD + dc0] = v0;
            out[(n * 9 + m) * CD + dc1] = v1;
          }
        }
      }
    }
  }
}

// =================== host: Wigner-3j (exact port of reference) ===================
typedef std::complex<double> cd;

static double factd(int n) { double r = 1.0; for (int i = 2; i <= n; ++i) r *= i; return r; }

static double su2_cg(int j1, int m1, int j2, int m2, int j3, int m3) {
  if (m3 != m1 + m2) return 0.0;
  int vmin = -j1 + j2 + m3; if (-j1 + m1 > vmin) vmin = -j1 + m1; if (0 > vmin) vmin = 0;
  int vmax = j2 + j3 + m1; if (j3 - j1 + j2 < vmax) vmax = j3 - j1 + j2; if (j3 + m3 < vmax) vmax = j3 + m3;
  double pref = std::sqrt((2.0 * j3 + 1.0) * factd(j3 + j1 - j2) * factd(j3 - j1 + j2)
                          * factd(j1 + j2 - j3) / factd(j1 + j2 + j3 + 1)
                          * factd(j3 + m3) * factd(j3 - m3)
                          / (factd(j1 - m1) * factd(j1 + m1) * factd(j2 - m2) * factd(j2 + m2)));
  double s = 0.0;
  for (int v = vmin; v <= vmax; ++v) {
    double sgn = ((v + j2 + m2) & 1) ? -1.0 : 1.0;
    s += sgn / factd(v) * factd(j2 + j3 + m1 - v) * factd(j1 - m1 + v)
         / (factd(j3 - j1 + j2 - v) * factd(j3 + m3 - v) * factd(v + j1 - j2 - m3));
  }
  return pref * s;
}

static void qmat(int l, cd q[5][5]) {
  for (int a = 0; a < 5; ++a) for (int b = 0; b < 5; ++b) q[a][b] = 0.0;
  const double is2 = 1.0 / std::sqrt(2.0);
  for (int m = -l; m < 0; ++m) {
    q[l + m][l - m] = is2;            // q[l+m, l+|m|]
    q[l + m][l + m] = cd(0.0, -is2);  // q[l+m, l-|m|]
  }
  q[l][l] = 1.0;
  for (int m = 1; m <= l; ++m) {
    double s = (m & 1) ? -1.0 : 1.0;
    q[l + m][l + m] = s * is2;
    q[l + m][l - m] = cd(0.0, s * is2);
  }
  cd f(1.0, 0.0);
  for (int i = 0; i < l; ++i) f *= cd(0.0, -1.0);  // (-1j)^l
  for (int a = 0; a < 5; ++a) for (int b = 0; b < 5; ++b) q[a][b] *= f;
}

static void wigner3j(int l1, int l2, int l3, double* C) {  // flat [d1][d2][d3]
  int d1 = 2 * l1 + 1, d2 = 2 * l2 + 1, d3 = 2 * l3 + 1;
  cd Q1[5][5], Q2[5][5], Q3[5][5];
  qmat(l1, Q1); qmat(l2, Q2); qmat(l3, Q3);
  cd Csu2[5][5][5];
  for (int i = 0; i < d1; ++i)
    for (int k = 0; k < d2; ++k)
      for (int n = 0; n < d3; ++n)
        Csu2[i][k][n] = su2_cg(l1, i - l1, l2, k - l2, l3, n - l3);
  double norm = 0.0;
  for (int j = 0; j < d1; ++j)
    for (int lx = 0; lx < d2; ++lx)
      for (int m = 0; m < d3; ++m) {
        cd acc(0.0, 0.0);
        for (int i = 0; i < d1; ++i)
          for (int k = 0; k < d2; ++k)
            for (int n = 0; n < d3; ++n)
              acc += Q1[i][j] * Q2[k][lx] * std::conj(Q3[n][m]) * Csu2[i][k][n];
        C[(j * d2 + lx) * d3 + m] = acc.real();
        norm += acc.real() * acc.real();
      }
  norm = std::sqrt(norm);
  for (int t = 0; t < d1 * d2 * d3; ++t) C[t] /= norm;
}

extern "C" void kernel_launch(void* const* d_in, const int* in_sizes, int n_in,
                              void* d_out, int out_size, void* d_ws, size_t ws_size,
                              hipStream_t stream) {
  const float* x    = (const float*)d_in[0];
  const float* Wl   = (const float*)d_in[1];
  const float* Wr   = (const float*)d_in[3];
  const float* Wf   = (const float*)d_in[5];
  const float* bfin = (const float*)d_in[6];
  float* out = (float*)d_out;
  const int N = in_sizes[0] / (9 * CD);

  TPW tw;
  double c220[25], c121[45], c112[45];
  wigner3j(2, 2, 0, c220);
  wigner3j(1, 2, 1, c121);
  wigner3j(1, 1, 2, c112);
  const double a1 = std::sqrt(3.0), a2 = std::sqrt(5.0);
  for (int i = 0; i < 25; ++i) tw.w220[i] = (float)c220[i];          // alpha = 1
  for (int i = 0; i < 45; ++i) tw.w121[i] = (float)(a1 * c121[i]);
  for (int i = 0; i < 45; ++i) tw.w112[i] = (float)(a2 * c112[i]);

  u16* ws = (u16*)d_ws;  // 147456 bf16 = 294912 B
  cvt_weights_kernel<<<72, 256, 0, stream>>>(Wl, Wr, Wf, ws);
  int grid = (N + TILE_N - 1) / TILE_N;
  fused_kernel<<<grid, 256, 0, stream>>>(x, ws, bfin, out, N, tw);
}